// Round 7
// baseline (573.105 us; speedup 1.0000x reference)
//
#include <hip/hip_runtime.h>
#include <hip/hip_bf16.h>
#include <math.h>

#define CDIM 512
#define NTOK 3136
#define BATCH 8
#define MTOT (BATCH*NTOK)   // 25088
#define NHEAD 8
#define DHEAD 64
#define HW 56

typedef __attribute__((ext_vector_type(8))) short short8;
typedef __attribute__((ext_vector_type(4))) float f32x4;

__device__ __forceinline__ ushort f2bf(float f) {
    union { float f; unsigned int u; } v; v.f = f;
    unsigned int u = v.u + 0x7FFFu + ((v.u >> 16) & 1u);
    return (ushort)(u >> 16);
}
__device__ __forceinline__ float bf2f(ushort u) {
    union { unsigned int u; float f; } v; v.u = ((unsigned int)u) << 16;
    return v.f;
}

__device__ __forceinline__ void gload_lds16(const void* g, void* lds) {
    __builtin_amdgcn_global_load_lds((const __attribute__((address_space(1))) void*)g,
                                     (__attribute__((address_space(3))) void*)lds,
                                     16, 0, 0);
}

// ---------------- prep: per-channel inv_scale and power ----------------
__global__ void prep_kernel(const float* __restrict__ scale_p,
                            const float* __restrict__ power_p,
                            float* __restrict__ inv_scale,
                            float* __restrict__ power) {
    int c = threadIdx.x;
    if (c < CDIM) {
        float s = log1pf(expf(scale_p[c]));        // softplus
        inv_scale[c] = 1.0f / s;
        power[c] = 1.0f + 4.0f / (1.0f + expf(-power_p[c]));  // 1+ALPHA*sigmoid
    }
}

// ---------------- fp32 -> bf16 conversion (vectorized) ----------------
__global__ __launch_bounds__(256) void cvt_bf16_kernel(const float* __restrict__ src,
                                                       ushort* __restrict__ dst, int n4) {
    int i = blockIdx.x * 256 + threadIdx.x;
    if (i < n4) {
        float4 f = ((const float4*)src)[i];
        ushort4 o;
        o.x = f2bf(f.x); o.y = f2bf(f.y); o.z = f2bf(f.z); o.w = f2bf(f.w);
        ((ushort4*)dst)[i] = o;
    }
}

// ---------------- merged qg+kv MFMA GEMM, XCD-swizzled, 2-phase pipelined ----------------
// 1D grid 3136 blocks. idp=(bid&7)*392+(bid>>3); mb=idp>>4, ob=idp&15.
// ob 0..7 -> qg weights (cols 0..1023: Q|G), ob 8..15 -> kv weights (cols 1024..2047: K->KF | V).
__global__ __launch_bounds__(256) void mgemm_qgkv(const ushort* __restrict__ A,
                                                  const ushort* __restrict__ Wqg,
                                                  const ushort* __restrict__ Wkv,
                                                  float* __restrict__ Qout,
                                                  float* __restrict__ Gout,
                                                  ushort* __restrict__ KFout,
                                                  ushort* __restrict__ Vout,
                                                  const float* __restrict__ pos,
                                                  const float* __restrict__ invs,
                                                  const float* __restrict__ powr) {
    __shared__ ushort At[2][128 * 64];
    __shared__ ushort Bt[2][128 * 64];
    const int t = threadIdx.x;
    const int w = t >> 6, l = t & 63;
    const int wr = w >> 1, wc = w & 1;
    const int r8 = l >> 3, sl = l & 7;
    const int ss = sl ^ r8;

    const int bid = blockIdx.x;
    const int idp = (bid & 7) * 392 + (bid >> 3);
    const int mb = idp >> 4, ob = idp & 15;
    const int m0 = mb * 128;
    const ushort* Bp = (ob < 8) ? (Wqg + (size_t)ob * 128 * CDIM)
                                : (Wkv + (size_t)(ob - 8) * 128 * CDIM);

    auto stage = [&](int buf, int ks) {
        const int k0 = ks * 64;
        #pragma unroll
        for (int c = 0; c < 4; ++c) {
            int rc = (w * 4 + c) * 8 + r8;
            gload_lds16(A + (size_t)(m0 + rc) * CDIM + k0 + ss * 8, &At[buf][(w * 4 + c) * 512]);
            gload_lds16(Bp + (size_t)rc * CDIM + k0 + ss * 8, &Bt[buf][(w * 4 + c) * 512]);
        }
    };

    f32x4 acc[4][4] = {};
    stage(0, 0);
    __syncthreads();
    int cur = 0;
    for (int ks = 0; ks < 8; ++ks) {
        if (ks < 7) stage(cur ^ 1, ks + 1);
        #pragma unroll
        for (int kk = 0; kk < 2; ++kk) {
            short8 af[4], bfr[4];
            const int sbase = kk * 4 + (l >> 4);
            #pragma unroll
            for (int i = 0; i < 4; ++i) {
                int row = wr * 64 + i * 16 + (l & 15);
                af[i] = *(const short8*)&At[cur][row * 64 + ((sbase ^ (row & 7)) * 8)];
                int rowb = wc * 64 + i * 16 + (l & 15);
                bfr[i] = *(const short8*)&Bt[cur][rowb * 64 + ((sbase ^ (rowb & 7)) * 8)];
            }
            #pragma unroll
            for (int i = 0; i < 4; ++i)
                #pragma unroll
                for (int j = 0; j < 4; ++j)
                    acc[i][j] = __builtin_amdgcn_mfma_f32_16x16x32_bf16(af[i], bfr[j], acc[i][j], 0, 0, 0);
        }
        __syncthreads();
        cur ^= 1;
    }

    #pragma unroll
    for (int i = 0; i < 4; ++i) {
        #pragma unroll
        for (int rr = 0; rr < 4; ++rr) {
            int m = m0 + wr * 64 + i * 16 + (l >> 4) * 4 + rr;
            size_t mrow = (size_t)m * CDIM;
            #pragma unroll
            for (int j = 0; j < 4; ++j) {
                int colg = ob * 128 + wc * 64 + j * 16 + (l & 15);
                float v = acc[i][j][rr];
                if (colg < 512) {
                    Qout[mrow + colg] = v;
                } else if (colg < 1024) {
                    Gout[mrow + colg - 512] = v;
                } else if (colg < 1536) {
                    int oc = colg - 1024;
                    int n = m % NTOK;
                    float kx = (v + pos[(size_t)n * CDIM + oc]) * invs[oc];
                    float tp = __powf(fabsf(kx), powr[oc]);
                    ushort* dst = KFout + ((size_t)m * 8 + (oc >> 6)) * 128 + (oc & 63);
                    dst[0]  = kx > 0.f ? f2bf(tp) : (ushort)0;
                    dst[64] = kx < 0.f ? f2bf(tp) : (ushort)0;
                } else {
                    Vout[mrow + colg - 1536] = f2bf(v);
                }
            }
        }
    }
}

// ---------------- proj MFMA GEMM, XCD-swizzled, 2-phase ----------------
// 784 blocks: idp=(bid&7)*98+(bid>>3); mb=idp>>2, ob=idp&3.
__global__ __launch_bounds__(256) void mgemm_proj(const ushort* __restrict__ A,
                                                  const ushort* __restrict__ W,
                                                  float* __restrict__ out,
                                                  const float* __restrict__ pb) {
    __shared__ ushort At[2][128 * 64];
    __shared__ ushort Bt[2][128 * 64];
    const int t = threadIdx.x;
    const int w = t >> 6, l = t & 63;
    const int wr = w >> 1, wc = w & 1;
    const int r8 = l >> 3, sl = l & 7;
    const int ss = sl ^ r8;

    const int bid = blockIdx.x;
    const int idp = (bid & 7) * 98 + (bid >> 3);
    const int mb = idp >> 2, ob = idp & 3;
    const int m0 = mb * 128;
    const ushort* Bp = W + (size_t)ob * 128 * CDIM;

    auto stage = [&](int buf, int ks) {
        const int k0 = ks * 64;
        #pragma unroll
        for (int c = 0; c < 4; ++c) {
            int rc = (w * 4 + c) * 8 + r8;
            gload_lds16(A + (size_t)(m0 + rc) * CDIM + k0 + ss * 8, &At[buf][(w * 4 + c) * 512]);
            gload_lds16(Bp + (size_t)rc * CDIM + k0 + ss * 8, &Bt[buf][(w * 4 + c) * 512]);
        }
    };

    f32x4 acc[4][4] = {};
    stage(0, 0);
    __syncthreads();
    int cur = 0;
    for (int ks = 0; ks < 8; ++ks) {
        if (ks < 7) stage(cur ^ 1, ks + 1);
        #pragma unroll
        for (int kk = 0; kk < 2; ++kk) {
            short8 af[4], bfr[4];
            const int sbase = kk * 4 + (l >> 4);
            #pragma unroll
            for (int i = 0; i < 4; ++i) {
                int row = wr * 64 + i * 16 + (l & 15);
                af[i] = *(const short8*)&At[cur][row * 64 + ((sbase ^ (row & 7)) * 8)];
                int rowb = wc * 64 + i * 16 + (l & 15);
                bfr[i] = *(const short8*)&Bt[cur][rowb * 64 + ((sbase ^ (rowb & 7)) * 8)];
            }
            #pragma unroll
            for (int i = 0; i < 4; ++i)
                #pragma unroll
                for (int j = 0; j < 4; ++j)
                    acc[i][j] = __builtin_amdgcn_mfma_f32_16x16x32_bf16(af[i], bfr[j], acc[i][j], 0, 0, 0);
        }
        __syncthreads();
        cur ^= 1;
    }

    #pragma unroll
    for (int i = 0; i < 4; ++i) {
        #pragma unroll
        for (int rr = 0; rr < 4; ++rr) {
            int m = m0 + wr * 64 + i * 16 + (l >> 4) * 4 + rr;
            size_t mrow = (size_t)m * CDIM;
            #pragma unroll
            for (int j = 0; j < 4; ++j) {
                int colg = ob * 128 + wc * 64 + j * 16 + (l & 15);
                out[mrow + colg] = acc[i][j][rr] + pb[colg];
            }
        }
    }
}

// ---------------- fused 3x3 depthwise conv + BN-stats accumulation ----------------
__global__ __launch_bounds__(256) void conv3s_kernel(const float* __restrict__ Q,
                                                     const float* __restrict__ enh_w,
                                                     float* __restrict__ QE,
                                                     float* __restrict__ ssum,
                                                     float* __restrict__ ssq) {
    const int t = threadIdx.x;
    const int c0 = t * 2;
    const int xpos = blockIdx.x;
    const int byc = blockIdx.y;
    const int b = byc >> 2, yc = byc & 3;
    const int y0 = yc * 14;

    float wgt[9][2];
    #pragma unroll
    for (int tap = 0; tap < 9; ++tap) {
        wgt[tap][0] = enh_w[c0 * 9 + tap];
        wgt[tap][1] = enh_w[(c0 + 1) * 9 + tap];
    }
    const size_t base = (size_t)b * NTOK * CDIM + c0;

    float2 win[3][3];
    auto ldrow = [&](int yy, float2* dst) {
        #pragma unroll
        for (int dx = 0; dx < 3; ++dx) {
            int xx = xpos + dx - 1;
            bool ok = (yy >= 0 && yy < HW && xx >= 0 && xx < HW);
            dst[dx] = ok ? *(const float2*)(Q + base + ((size_t)(yy * HW + xx) << 9))
                         : make_float2(0.f, 0.f);
        }
    };
    ldrow(y0 - 1, win[0]);
    ldrow(y0,     win[1]);

    float s1a = 0.f, s2a = 0.f, s1b = 0.f, s2b = 0.f;
    #pragma unroll
    for (int i = 0; i < 14; ++i) {
        int y = y0 + i;
        ldrow(y + 1, win[(i + 2) % 3]);
        float a0 = 0.f, a1 = 0.f;
        #pragma unroll
        for (int dy = 0; dy < 3; ++dy) {
            float2* row = win[(i + dy) % 3];
            #pragma unroll
            for (int dx = 0; dx < 3; ++dx) {
                a0 = fmaf(row[dx].x, wgt[dy * 3 + dx][0], a0);
                a1 = fmaf(row[dx].y, wgt[dy * 3 + dx][1], a1);
            }
        }
        *(float2*)(QE + base + ((size_t)(y * HW + xpos) << 9)) = make_float2(a0, a1);
        s1a += a0; s2a += a0 * a0;
        s1b += a1; s2b += a1 * a1;
    }
    atomicAdd(&ssum[c0], s1a);     atomicAdd(&ssq[c0], s2a);
    atomicAdd(&ssum[c0 + 1], s1b); atomicAdd(&ssq[c0 + 1], s2b);
}

__global__ void bnprep_kernel(const float* __restrict__ ssum, const float* __restrict__ ssq,
                              const float* __restrict__ bn_g, const float* __restrict__ bn_b,
                              float* __restrict__ achan, float* __restrict__ bchan) {
    int c = threadIdx.x;
    if (c < CDIM) {
        const float invM = 1.0f / (float)MTOT;
        float mean = ssum[c] * invM;
        float var  = ssq[c] * invM - mean * mean;
        float a = bn_g[c] * rsqrtf(var + 1e-5f);
        achan[c] = a;
        bchan[c] = bn_b[c] - mean * a;
    }
}

// ---------------- finalize q: Q = (Q + ew*relu(a*QE+b)) * inv_scale ----------------
__global__ __launch_bounds__(256) void qfin_kernel(float* __restrict__ Q,
                                                   const float* __restrict__ QE,
                                                   const float* __restrict__ achan,
                                                   const float* __restrict__ bchan,
                                                   const float* __restrict__ inv_scale,
                                                   const float* __restrict__ ewp) {
    int gid = blockIdx.x * 256 + threadIdx.x;
    int c = gid & (CDIM - 1);
    float ew = ewp[0];
    float e = fmaxf(fmaf(achan[c], QE[gid], bchan[c]), 0.f);
    Q[gid] = fmaf(ew, e, Q[gid]) * inv_scale[c];
}

// ---------------- kvred v4: zero-LDS register MFMA GEMM over precomputed KFbf/Vbf ----------
__global__ __launch_bounds__(256) void kvred4_kernel(const ushort* __restrict__ KF,
                                                     const ushort* __restrict__ Vbf,
                                                     float* __restrict__ PKV) {
    const int bh = blockIdx.x, chunk = blockIdx.y;
    const int b = bh >> 3, head = bh & 7;
    const int t = threadIdx.x;
    const int w = t >> 6, l = t & 63;
    const int lr = l & 15;
    const int ns = (l >> 4) * 8;

    const int nbase = b * NTOK + chunk * 224;
    const ushort* kf0 = KF  + ((size_t)(nbase + ns)) * 1024 + head * 128 + (w * 32 + lr);
    const ushort* vb0 = Vbf + ((size_t)(nbase + ns)) * 512  + head * 64  + lr;

    short8 ones;
    #pragma unroll
    for (int j = 0; j < 8; ++j) ones[j] = (lr == 0) ? (short)0x3F80 : (short)0;

    f32x4 acc[2][5] = {};
    for (int tile = 0; tile < 7; ++tile) {
        union { uint u[4]; short8 s; } ua[2], ub[4];
        #pragma unroll
        for (int i = 0; i < 2; ++i) {
            #pragma unroll
            for (int j = 0; j < 4; ++j) {
                uint lo = kf0[i * 16 + (size_t)(2 * j) * 1024];
                uint hi = kf0[i * 16 + (size_t)(2 * j + 1) * 1024];
                ua[i].u[j] = lo | (hi << 16);
            }
        }
        #pragma unroll
        for (int j5 = 0; j5 < 4; ++j5) {
            #pragma unroll
            for (int j = 0; j < 4; ++j) {
                uint lo = vb0[j5 * 16 + (size_t)(2 * j) * 512];
                uint hi = vb0[j5 * 16 + (size_t)(2 * j + 1) * 512];
                ub[j5].u[j] = lo | (hi << 16);
            }
        }
        #pragma unroll
        for (int i = 0; i < 2; ++i) {
            #pragma unroll
            for (int j5 = 0; j5 < 4; ++j5)
                acc[i][j5] = __builtin_amdgcn_mfma_f32_16x16x32_bf16(ua[i].s, ub[j5].s, acc[i][j5], 0, 0, 0);
            acc[i][4] = __builtin_amdgcn_mfma_f32_16x16x32_bf16(ua[i].s, ones, acc[i][4], 0, 0, 0);
        }
        kf0 += (size_t)32 * 1024;
        vb0 += (size_t)32 * 512;
    }
    size_t base = ((size_t)(chunk * 64 + bh)) * 8320;
    #pragma unroll
    for (int i = 0; i < 2; ++i) {
        int d0 = w * 32 + i * 16 + (l >> 4) * 4;
        #pragma unroll
        for (int j = 0; j < 5; ++j) {
            int e = j * 16 + lr;
            if (j < 4 || e == 64)
                *(f32x4*)(PKV + base + (size_t)e * 128 + d0) = acc[i][j];
        }
    }
}

// reduce partials: kvT[bh][e=64][d=128], kmean[bh][128]
__global__ __launch_bounds__(256) void kvreduce_kernel(const float* __restrict__ PKV,
                                                       float* __restrict__ kvT,
                                                       float* __restrict__ kmean) {
    int gid = blockIdx.x * 256 + threadIdx.x;
    const float inv_n = 1.0f / (float)NTOK;
    float s = 0.f;
    #pragma unroll
    for (int c = 0; c < 14; ++c) s += PKV[(size_t)c * 532480 + gid];
    s *= inv_n;
    int bh = gid / 8320;
    int r  = gid - bh * 8320;
    int e = r >> 7, d = r & 127;
    if (e < 64) kvT[(size_t)bh * 8192 + e * 128 + d] = s;
    else        kmean[bh * 128 + d] = s;
}

// ---------------- attention apply via MFMA: [64 tok][128] x [128][80] ----------------
__global__ __launch_bounds__(256) void attn_mfma_kernel(const float* __restrict__ Q,
                                                        const float* __restrict__ kvT,
                                                        const float* __restrict__ kmean,
                                                        const float* __restrict__ power,
                                                        float* __restrict__ ATT) {
    __shared__ ushort QF[64 * 128];
    __shared__ ushort BT[80 * 128];
    const int bh = blockIdx.x, tb = blockIdx.y;
    const int b = bh >> 3, head = bh & 7;
    const int t = threadIdx.x;
    const int w = t >> 6, l = t & 63;

    const int c = l;
    const float p = power[head * 64 + c];
    #pragma unroll
    for (int i = 0; i < 16; ++i) {
        int tok = i * 4 + w;
        float q = Q[((size_t)(b * NTOK + tb * 64 + tok)) * CDIM + head * 64 + c];
        float ax = fabsf(q);
        float tp = ax > 0.f ? __powf(ax, p) : 0.f;
        float qp = q > 0.f ? tp : 0.f;
        float qn = q < 0.f ? tp : 0.f;
        int sw = tok & 7;
        QF[tok * 128 + (((c >> 3) ^ sw) * 8) + (c & 7)]       = f2bf(qp);
        QF[tok * 128 + ((((c >> 3) + 8) ^ sw) * 8) + (c & 7)] = f2bf(qn);
    }
    #pragma unroll
    for (int i = 0; i < 5; ++i) {
        int qc = i * 256 + t;
        int row = qc >> 4, s = qc & 15;
        int ls = s ^ (row & 7);
        int d0 = ls * 8;
        short8 ov;
        if (row < 64) {
            int dsel = (row >= 32) ? (d0 ^ 64) : d0;
            const float* src = kvT + (size_t)bh * 8192 + row * 128 + dsel;
            #pragma unroll
            for (int e = 0; e < 8; ++e) ov[e] = (short)f2bf(src[e]);
        } else if (row == 64) {
            const float* src = kmean + bh * 128 + d0;
            #pragma unroll
            for (int e = 0; e < 8; ++e) ov[e] = (short)f2bf(src[e]);
        } else if (row == 65) {
            const float* src = kmean + bh * 128 + (d0 ^ 64);
            #pragma unroll
            for (int e = 0; e < 8; ++e) ov[e] = (short)f2bf(src[e]);
        } else {
            #pragma unroll
            for (int e = 0; e < 8; ++e) ov[e] = 0;
        }
        *(short8*)&BT[row * 128 + s * 8] = ov;
    }
    __syncthreads();

    f32x4 acc[5] = {};
    #pragma unroll
    for (int kk = 0; kk < 4; ++kk) {
        int sbase = kk * 4 + (l >> 4);
        int rowa = w * 16 + (l & 15);
        short8 af = *(const short8*)&QF[rowa * 128 + ((sbase ^ (rowa & 7)) * 8)];
        #pragma unroll
        for (int j = 0; j < 5; ++j) {
            int rowb = j * 16 + (l & 15);
            short8 bf = *(const short8*)&BT[rowb * 128 + ((sbase ^ (rowb & 7)) * 8)];
            acc[j] = __builtin_amdgcn_mfma_f32_16x16x32_bf16(af, bf, acc[j], 0, 0, 0);
        }
    }
    #pragma unroll
    for (int rr = 0; rr < 4; ++rr) {
        float ssim = __shfl(acc[4][rr], (l & 48));
        float sopp = __shfl(acc[4][rr], (l & 48) + 1);
        float zs = 1.f / (ssim + 1e-6f);
        float zo = 1.f / (sopp + 1e-6f);
        int tok = tb * 64 + w * 16 + (l >> 4) * 4 + rr;
        size_t base = ((size_t)(b * NTOK + tok)) * CDIM + head * 64;
        #pragma unroll
        for (int j = 0; j < 4; ++j) {
            int e = j * 16 + (l & 15);
            ATT[base + e] = acc[j][rr] * (j < 2 ? zs : zo);
        }
    }
}

// ---------------- v 5x5 depthwise conv (bf16 V) + gate ----------------
__global__ __launch_bounds__(256) void voutg2_kernel(const ushort* __restrict__ Vbf,
                                                     const float* __restrict__ ATT,
                                                     const float* __restrict__ G,
                                                     const float* __restrict__ dwc_w,
                                                     const float* __restrict__ dwc_b,
                                                     ushort* __restrict__ PRE) {
    const int t = threadIdx.x;
    const int c0 = t * 2;
    const int xpos = blockIdx.x;
    const int byc = blockIdx.y;
    const int b = byc >> 2, yc = byc & 3;
    const int y0 = yc * 14;
    const int dch = c0 & 63;

    float wgt[25][2];
    #pragma unroll
    for (int tap = 0; tap < 25; ++tap) {
        wgt[tap][0] = dwc_w[dch * 25 + tap];
        wgt[tap][1] = dwc_w[(dch + 1) * 25 + tap];
    }
    const float bias0 = dwc_b[dch], bias1 = dwc_b[dch + 1];
    const size_t base = (size_t)b * NTOK * CDIM + c0;

    float2 win[5][5];
    auto ldrow = [&](int yy, float2* dst) {
        #pragma unroll
        for (int dx = 0; dx < 5; ++dx) {
            int xx = xpos + dx - 2;
            bool ok = (yy >= 0 && yy < HW && xx >= 0 && xx < HW);
            if (ok) {
                ushort2 uv = *(const ushort2*)(Vbf + base + ((size_t)(yy * HW + xx) << 9));
                dst[dx] = make_float2(bf2f(uv.x), bf2f(uv.y));
            } else {
                dst[dx] = make_float2(0.f, 0.f);
            }
        }
    };
    ldrow(y0 - 2, win[0]);
    ldrow(y0 - 1, win[1]);
    ldrow(y0,     win[2]);
    ldrow(y0 + 1, win[3]);

    #pragma unroll
    for (int i = 0; i < 14; ++i) {
        int y = y0 + i;
        ldrow(y + 2, win[(i + 4) % 5]);
        float a0 = bias0, a1 = bias1;
        #pragma unroll
        for (int dy = 0; dy < 5; ++dy) {
            float2* row = win[(i + dy) % 5];
            #pragma unroll
            for (int dx = 0; dx < 5; ++dx) {
                a0 = fmaf(row[dx].x, wgt[dy * 5 + dx][0], a0);
                a1 = fmaf(row[dx].y, wgt[dy * 5 + dx][1], a1);
            }
        }
        size_t oidx = base + ((size_t)(y * HW + xpos) << 9);
        float2 att = *(const float2*)(ATT + oidx);
        float2 g   = *(const float2*)(G + oidx);
        ushort2 o;
        o.x = f2bf((att.x + a0) * g.x);
        o.y = f2bf((att.y + a1) * g.y);
        *(ushort2*)(PRE + oidx) = o;
    }
}

extern "C" void kernel_launch(void* const* d_in, const int* in_sizes, int n_in,
                              void* d_out, int out_size, void* d_ws, size_t ws_size,
                              hipStream_t stream) {
    const float* x      = (const float*)d_in[0];
    const float* qg_w   = (const float*)d_in[1];
    const float* kv_w   = (const float*)d_in[2];
    const float* proj_w = (const float*)d_in[3];
    const float* proj_b = (const float*)d_in[4];
    const float* dwc_w  = (const float*)d_in[5];
    const float* dwc_b  = (const float*)d_in[6];
    const float* power_p= (const float*)d_in[7];
    const float* scale_p= (const float*)d_in[8];
    const float* enh_w  = (const float*)d_in[9];
    const float* bn_g   = (const float*)d_in[10];
    const float* bn_b   = (const float*)d_in[11];
    const float* ew_p   = (const float*)d_in[12];
    const float* pos    = (const float*)d_in[13];

    const size_t NELEM = (size_t)MTOT * CDIM;   // 12,845,056
    float* ws    = (float*)d_ws;
    float* Qb    = ws;                  // fp32 Q
    float* Gb    = ws + NELEM;          // fp32 G
    float* Kb    = ws + 2 * NELEM;      // KFbf ushort [MTOT][1024]; later PREbf
    float* Vb    = ws + 3 * NELEM;      // Vbf ushort [MTOT][512]
    float* QEb   = ws + 4 * NELEM;      // reused: Xbf, QE, PKV, ATT
    float* SMALL = ws + 5 * NELEM;
    float* ssum  = SMALL;               // 512
    float* ssq   = SMALL + 512;         // 512
    float* kmean = SMALL + 1024;        // 8192
    float* kvT   = SMALL + 9216;        // 524288 ([bh][e][d])
    float* invs  = SMALL + 533504;      // 512
    float* powr  = SMALL + 534016;      // 512
    float* achan = SMALL + 534528;      // 512
    float* bchan = SMALL + 535040;      // 512
    ushort* Wqg  = (ushort*)(SMALL + 535552);    // 524288 bf16
    ushort* Wkv  = (ushort*)(SMALL + 797696);    // 524288 bf16
    ushort* Wproj= (ushort*)(SMALL + 1059840);   // 262144 bf16

    ushort* Xbf  = (ushort*)QEb;        // x bf16 (dead after qgkv gemm; conv3 overwrites)
    ushort* KFbf = (ushort*)Kb;         // dead after kvred4
    ushort* Vbf  = (ushort*)Vb;
    float* PKV   = QEb;                 // 14*532480 floats (QE dead after qfin)
    float* ATTb  = QEb;                 // attn output (partials dead after kvreduce)
    ushort* PREbf= (ushort*)Kb;         // proj input bf16 (KFbf dead after kvred4)

    hipMemsetAsync(SMALL, 0, (size_t)1024 * sizeof(float), stream);

    prep_kernel<<<1, 512, 0, stream>>>(scale_p, power_p, invs, powr);

    cvt_bf16_kernel<<<12544, 256, 0, stream>>>(x, Xbf, 3211264);
    cvt_bf16_kernel<<<512, 256, 0, stream>>>(qg_w, Wqg, 131072);
    cvt_bf16_kernel<<<512, 256, 0, stream>>>(kv_w, Wkv, 131072);
    cvt_bf16_kernel<<<256, 256, 0, stream>>>(proj_w, Wproj, 65536);

    mgemm_qgkv<<<3136, 256, 0, stream>>>(Xbf, Wqg, Wkv, Qb, Gb, KFbf, Vbf, pos, invs, powr);

    dim3 cgrid(56, 32);
    conv3s_kernel<<<cgrid, 256, 0, stream>>>(Qb, enh_w, QEb, ssum, ssq);
    bnprep_kernel<<<1, 512, 0, stream>>>(ssum, ssq, bn_g, bn_b, achan, bchan);
    qfin_kernel<<<50176, 256, 0, stream>>>(Qb, QEb, achan, bchan, invs, ew_p);

    kvred4_kernel<<<dim3(64, 14), 256, 0, stream>>>(KFbf, Vbf, PKV);
    kvreduce_kernel<<<2080, 256, 0, stream>>>(PKV, kvT, kmean);

    attn_mfma_kernel<<<dim3(64, 49), 256, 0, stream>>>(Qb, kvT, kmean, powr, ATTb);

    voutg2_kernel<<<cgrid, 256, 0, stream>>>(Vbf, ATTb, Gb, dwc_w, dwc_b, PREbf);

    mgemm_proj<<<784, 256, 0, stream>>>(PREbf, Wproj, (float*)d_out, proj_b);
}

// Round 8
// 498.491 us; speedup vs baseline: 1.1497x; 1.1497x over previous
//
#include <hip/hip_runtime.h>
#include <hip/hip_bf16.h>
#include <math.h>

#define CDIM 512
#define NTOK 3136
#define BATCH 8
#define MTOT (BATCH*NTOK)   // 25088
#define NHEAD 8
#define DHEAD 64
#define HW 56

typedef __attribute__((ext_vector_type(8))) short short8;
typedef __attribute__((ext_vector_type(4))) float f32x4;

__device__ __forceinline__ ushort f2bf(float f) {
    union { float f; unsigned int u; } v; v.f = f;
    unsigned int u = v.u + 0x7FFFu + ((v.u >> 16) & 1u);
    return (ushort)(u >> 16);
}
__device__ __forceinline__ float bf2f(ushort u) {
    union { unsigned int u; float f; } v; v.u = ((unsigned int)u) << 16;
    return v.f;
}

__device__ __forceinline__ void gload_lds16(const void* g, void* lds) {
    __builtin_amdgcn_global_load_lds((const __attribute__((address_space(1))) void*)g,
                                     (__attribute__((address_space(3))) void*)lds,
                                     16, 0, 0);
}

// ---------------- prep: per-channel inv_scale and power ----------------
__global__ void prep_kernel(const float* __restrict__ scale_p,
                            const float* __restrict__ power_p,
                            float* __restrict__ inv_scale,
                            float* __restrict__ power) {
    int c = threadIdx.x;
    if (c < CDIM) {
        float s = log1pf(expf(scale_p[c]));
        inv_scale[c] = 1.0f / s;
        power[c] = 1.0f + 4.0f / (1.0f + expf(-power_p[c]));
    }
}

// ---------------- fp32 -> bf16 conversion (vectorized) ----------------
__global__ __launch_bounds__(256) void cvt_bf16_kernel(const float* __restrict__ src,
                                                       ushort* __restrict__ dst, int n4) {
    int i = blockIdx.x * 256 + threadIdx.x;
    if (i < n4) {
        float4 f = ((const float4*)src)[i];
        ushort4 o;
        o.x = f2bf(f.x); o.y = f2bf(f.y); o.z = f2bf(f.z); o.w = f2bf(f.w);
        ((ushort4*)dst)[i] = o;
    }
}

// ---------------- merged qg+kv MFMA GEMM, XCD-swizzled, 2-phase, LDS epilogue ----------------
// 1D grid 3136. idp=(bid&7)*392+(bid>>3); mb=idp>>4, ob=idp&15.
// colg = ob*128: [0,512) Q fp32 | [512,1024) G fp32 | [1024,1536) K->KF bf16 | [1536,2048) V bf16.
__global__ __launch_bounds__(256) void mgemm_qgkv(const ushort* __restrict__ A,
                                                  const ushort* __restrict__ Wqg,
                                                  const ushort* __restrict__ Wkv,
                                                  float* __restrict__ Qout,
                                                  float* __restrict__ Gout,
                                                  ushort* __restrict__ KFout,
                                                  ushort* __restrict__ Vout,
                                                  const float* __restrict__ pos,
                                                  const float* __restrict__ invs,
                                                  const float* __restrict__ powr) {
    __shared__ __align__(16) char smem[65536];
    ushort* At = (ushort*)smem;               // [2][128*64]
    ushort* Bt = (ushort*)(smem + 32768);     // [2][128*64]
    float*  Osh = (float*)smem;               // epilogue alias [128*128]

    const int t = threadIdx.x;
    const int w = t >> 6, l = t & 63;
    const int wr = w >> 1, wc = w & 1;
    const int r8 = l >> 3, sl = l & 7;
    const int ss = sl ^ r8;

    const int bid = blockIdx.x;
    const int idp = (bid & 7) * 392 + (bid >> 3);
    const int mb = idp >> 4, ob = idp & 15;
    const int m0 = mb * 128;
    const ushort* Bp = (ob < 8) ? (Wqg + (size_t)ob * 128 * CDIM)
                                : (Wkv + (size_t)(ob - 8) * 128 * CDIM);

    auto stage = [&](int buf, int ks) {
        const int k0 = ks * 64;
        #pragma unroll
        for (int c = 0; c < 4; ++c) {
            int rc = (w * 4 + c) * 8 + r8;
            gload_lds16(A + (size_t)(m0 + rc) * CDIM + k0 + ss * 8, At + buf * 8192 + (w * 4 + c) * 512);
            gload_lds16(Bp + (size_t)rc * CDIM + k0 + ss * 8, Bt + buf * 8192 + (w * 4 + c) * 512);
        }
    };

    f32x4 acc[4][4] = {};
    stage(0, 0);
    __syncthreads();
    for (int ks = 0; ks < 8; ++ks) {
        int cur = ks & 1;
        if (ks < 7) stage(cur ^ 1, ks + 1);
        #pragma unroll
        for (int kk = 0; kk < 2; ++kk) {
            short8 af[4], bfr[4];
            const int sbase = kk * 4 + (l >> 4);
            #pragma unroll
            for (int i = 0; i < 4; ++i) {
                int row = wr * 64 + i * 16 + (l & 15);
                af[i] = *(const short8*)&At[cur * 8192 + row * 64 + ((sbase ^ (row & 7)) * 8)];
                int rowb = wc * 64 + i * 16 + (l & 15);
                bfr[i] = *(const short8*)&Bt[cur * 8192 + rowb * 64 + ((sbase ^ (rowb & 7)) * 8)];
            }
            #pragma unroll
            for (int i = 0; i < 4; ++i)
                #pragma unroll
                for (int j = 0; j < 4; ++j)
                    acc[i][j] = __builtin_amdgcn_mfma_f32_16x16x32_bf16(af[i], bfr[j], acc[i][j], 0, 0, 0);
        }
        __syncthreads();
    }

    // acc -> LDS (staging buffers dead)
    #pragma unroll
    for (int i = 0; i < 4; ++i)
        #pragma unroll
        for (int j = 0; j < 4; ++j)
            #pragma unroll
            for (int rr = 0; rr < 4; ++rr)
                Osh[(wr * 64 + i * 16 + (l >> 4) * 4 + rr) * 128 + wc * 64 + j * 16 + (l & 15)] = acc[i][j][rr];
    __syncthreads();

    // coalesced wide stores
    const int colbase = ob * 128;
    if (colbase < 512) {
        #pragma unroll
        for (int q = 0; q < 16; ++q) {
            int fi = q * 256 + t;
            int r = fi >> 5, c4 = (fi & 31) * 4;
            float4 v = *(float4*)&Osh[r * 128 + c4];
            *(float4*)&Qout[(size_t)(m0 + r) * CDIM + colbase + c4] = v;
        }
    } else if (colbase < 1024) {
        #pragma unroll
        for (int q = 0; q < 16; ++q) {
            int fi = q * 256 + t;
            int r = fi >> 5, c4 = (fi & 31) * 4;
            float4 v = *(float4*)&Osh[r * 128 + c4];
            *(float4*)&Gout[(size_t)(m0 + r) * CDIM + colbase - 512 + c4] = v;
        }
    } else if (colbase < 1536) {
        #pragma unroll
        for (int q = 0; q < 16; ++q) {
            int fi = q * 256 + t;
            int r = fi >> 5, c4 = (fi & 31) * 4;
            float4 v = *(float4*)&Osh[r * 128 + c4];
            int m = m0 + r;
            int n = m % NTOK;
            int oc = colbase - 1024 + c4;
            float4 pv = *(const float4*)&pos[(size_t)n * CDIM + oc];
            float4 iv = *(const float4*)&invs[oc];
            float4 pw = *(const float4*)&powr[oc];
            float kx0 = (v.x + pv.x) * iv.x, kx1 = (v.y + pv.y) * iv.y;
            float kx2 = (v.z + pv.z) * iv.z, kx3 = (v.w + pv.w) * iv.w;
            float t0 = __powf(fabsf(kx0), pw.x), t1 = __powf(fabsf(kx1), pw.y);
            float t2 = __powf(fabsf(kx2), pw.z), t3 = __powf(fabsf(kx3), pw.w);
            ushort4 up, un;
            up.x = kx0 > 0.f ? f2bf(t0) : 0; un.x = kx0 < 0.f ? f2bf(t0) : 0;
            up.y = kx1 > 0.f ? f2bf(t1) : 0; un.y = kx1 < 0.f ? f2bf(t1) : 0;
            up.z = kx2 > 0.f ? f2bf(t2) : 0; un.z = kx2 < 0.f ? f2bf(t2) : 0;
            up.w = kx3 > 0.f ? f2bf(t3) : 0; un.w = kx3 < 0.f ? f2bf(t3) : 0;
            ushort* dst = KFout + (size_t)m * 1024 + ((oc >> 6) << 7) + (oc & 63);
            *(ushort4*)dst = up;
            *(ushort4*)(dst + 64) = un;
        }
    } else {
        #pragma unroll
        for (int q = 0; q < 16; ++q) {
            int fi = q * 256 + t;
            int r = fi >> 5, c4 = (fi & 31) * 4;
            float4 v = *(float4*)&Osh[r * 128 + c4];
            ushort4 o;
            o.x = f2bf(v.x); o.y = f2bf(v.y); o.z = f2bf(v.z); o.w = f2bf(v.w);
            *(ushort4*)&Vout[(size_t)(m0 + r) * CDIM + colbase - 1536 + c4] = o;
        }
    }
}

// ---------------- proj MFMA GEMM, XCD-swizzled, 2-phase, LDS epilogue ----------------
__global__ __launch_bounds__(256) void mgemm_proj(const ushort* __restrict__ A,
                                                  const ushort* __restrict__ W,
                                                  float* __restrict__ out,
                                                  const float* __restrict__ pb) {
    __shared__ __align__(16) char smem[65536];
    ushort* At = (ushort*)smem;
    ushort* Bt = (ushort*)(smem + 32768);
    float*  Osh = (float*)smem;

    const int t = threadIdx.x;
    const int w = t >> 6, l = t & 63;
    const int wr = w >> 1, wc = w & 1;
    const int r8 = l >> 3, sl = l & 7;
    const int ss = sl ^ r8;

    const int bid = blockIdx.x;
    const int idp = (bid & 7) * 98 + (bid >> 3);
    const int mb = idp >> 2, ob = idp & 3;
    const int m0 = mb * 128;
    const ushort* Bp = W + (size_t)ob * 128 * CDIM;

    auto stage = [&](int buf, int ks) {
        const int k0 = ks * 64;
        #pragma unroll
        for (int c = 0; c < 4; ++c) {
            int rc = (w * 4 + c) * 8 + r8;
            gload_lds16(A + (size_t)(m0 + rc) * CDIM + k0 + ss * 8, At + buf * 8192 + (w * 4 + c) * 512);
            gload_lds16(Bp + (size_t)rc * CDIM + k0 + ss * 8, Bt + buf * 8192 + (w * 4 + c) * 512);
        }
    };

    f32x4 acc[4][4] = {};
    stage(0, 0);
    __syncthreads();
    for (int ks = 0; ks < 8; ++ks) {
        int cur = ks & 1;
        if (ks < 7) stage(cur ^ 1, ks + 1);
        #pragma unroll
        for (int kk = 0; kk < 2; ++kk) {
            short8 af[4], bfr[4];
            const int sbase = kk * 4 + (l >> 4);
            #pragma unroll
            for (int i = 0; i < 4; ++i) {
                int row = wr * 64 + i * 16 + (l & 15);
                af[i] = *(const short8*)&At[cur * 8192 + row * 64 + ((sbase ^ (row & 7)) * 8)];
                int rowb = wc * 64 + i * 16 + (l & 15);
                bfr[i] = *(const short8*)&Bt[cur * 8192 + rowb * 64 + ((sbase ^ (rowb & 7)) * 8)];
            }
            #pragma unroll
            for (int i = 0; i < 4; ++i)
                #pragma unroll
                for (int j = 0; j < 4; ++j)
                    acc[i][j] = __builtin_amdgcn_mfma_f32_16x16x32_bf16(af[i], bfr[j], acc[i][j], 0, 0, 0);
        }
        __syncthreads();
    }

    #pragma unroll
    for (int i = 0; i < 4; ++i)
        #pragma unroll
        for (int j = 0; j < 4; ++j)
            #pragma unroll
            for (int rr = 0; rr < 4; ++rr)
                Osh[(wr * 64 + i * 16 + (l >> 4) * 4 + rr) * 128 + wc * 64 + j * 16 + (l & 15)] = acc[i][j][rr];
    __syncthreads();

    const int colbase = ob * 128;
    #pragma unroll
    for (int q = 0; q < 16; ++q) {
        int fi = q * 256 + t;
        int r = fi >> 5, c4 = (fi & 31) * 4;
        float4 v = *(float4*)&Osh[r * 128 + c4];
        float4 b4 = *(const float4*)&pb[colbase + c4];
        v.x += b4.x; v.y += b4.y; v.z += b4.z; v.w += b4.w;
        *(float4*)&out[(size_t)(m0 + r) * CDIM + colbase + c4] = v;
    }
}

// ---------------- fused 3x3 depthwise conv + BN-stats accumulation ----------------
__global__ __launch_bounds__(256) void conv3s_kernel(const float* __restrict__ Q,
                                                     const float* __restrict__ enh_w,
                                                     float* __restrict__ QE,
                                                     float* __restrict__ ssum,
                                                     float* __restrict__ ssq) {
    const int t = threadIdx.x;
    const int c0 = t * 2;
    const int xpos = blockIdx.x;
    const int byc = blockIdx.y;
    const int b = byc >> 2, yc = byc & 3;
    const int y0 = yc * 14;

    float wgt[9][2];
    #pragma unroll
    for (int tap = 0; tap < 9; ++tap) {
        wgt[tap][0] = enh_w[c0 * 9 + tap];
        wgt[tap][1] = enh_w[(c0 + 1) * 9 + tap];
    }
    const size_t base = (size_t)b * NTOK * CDIM + c0;

    float2 win[3][3];
    auto ldrow = [&](int yy, float2* dst) {
        #pragma unroll
        for (int dx = 0; dx < 3; ++dx) {
            int xx = xpos + dx - 1;
            bool ok = (yy >= 0 && yy < HW && xx >= 0 && xx < HW);
            dst[dx] = ok ? *(const float2*)(Q + base + ((size_t)(yy * HW + xx) << 9))
                         : make_float2(0.f, 0.f);
        }
    };
    ldrow(y0 - 1, win[0]);
    ldrow(y0,     win[1]);

    float s1a = 0.f, s2a = 0.f, s1b = 0.f, s2b = 0.f;
    #pragma unroll
    for (int i = 0; i < 14; ++i) {
        int y = y0 + i;
        ldrow(y + 1, win[(i + 2) % 3]);
        float a0 = 0.f, a1 = 0.f;
        #pragma unroll
        for (int dy = 0; dy < 3; ++dy) {
            float2* row = win[(i + dy) % 3];
            #pragma unroll
            for (int dx = 0; dx < 3; ++dx) {
                a0 = fmaf(row[dx].x, wgt[dy * 3 + dx][0], a0);
                a1 = fmaf(row[dx].y, wgt[dy * 3 + dx][1], a1);
            }
        }
        *(float2*)(QE + base + ((size_t)(y * HW + xpos) << 9)) = make_float2(a0, a1);
        s1a += a0; s2a += a0 * a0;
        s1b += a1; s2b += a1 * a1;
    }
    atomicAdd(&ssum[c0], s1a);     atomicAdd(&ssq[c0], s2a);
    atomicAdd(&ssum[c0 + 1], s1b); atomicAdd(&ssq[c0 + 1], s2b);
}

__global__ void bnprep_kernel(const float* __restrict__ ssum, const float* __restrict__ ssq,
                              const float* __restrict__ bn_g, const float* __restrict__ bn_b,
                              float* __restrict__ achan, float* __restrict__ bchan) {
    int c = threadIdx.x;
    if (c < CDIM) {
        const float invM = 1.0f / (float)MTOT;
        float mean = ssum[c] * invM;
        float var  = ssq[c] * invM - mean * mean;
        float a = bn_g[c] * rsqrtf(var + 1e-5f);
        achan[c] = a;
        bchan[c] = bn_b[c] - mean * a;
    }
}

// ---------------- kvred v4: zero-LDS register MFMA GEMM over KFbf/Vbf ----------
// grid (64 bh, 7 chunks), 448 rows = 14 tiles of 32. PKV[(chunk*64+bh)][e=65][d=128].
__global__ __launch_bounds__(256) void kvred4_kernel(const ushort* __restrict__ KF,
                                                     const ushort* __restrict__ Vbf,
                                                     float* __restrict__ PKV) {
    const int bh = blockIdx.x, chunk = blockIdx.y;
    const int b = bh >> 3, head = bh & 7;
    const int t = threadIdx.x;
    const int w = t >> 6, l = t & 63;
    const int lr = l & 15;
    const int ns = (l >> 4) * 8;

    const int nbase = b * NTOK + chunk * 448;
    const ushort* kf0 = KF  + ((size_t)(nbase + ns)) * 1024 + head * 128 + (w * 32 + lr);
    const ushort* vb0 = Vbf + ((size_t)(nbase + ns)) * 512  + head * 64  + lr;

    short8 ones;
    #pragma unroll
    for (int j = 0; j < 8; ++j) ones[j] = (lr == 0) ? (short)0x3F80 : (short)0;

    f32x4 acc[2][5] = {};
    for (int tile = 0; tile < 14; ++tile) {
        union { uint u[4]; short8 s; } ua[2], ub[4];
        #pragma unroll
        for (int i = 0; i < 2; ++i) {
            #pragma unroll
            for (int j = 0; j < 4; ++j) {
                uint lo = kf0[i * 16 + (size_t)(2 * j) * 1024];
                uint hi = kf0[i * 16 + (size_t)(2 * j + 1) * 1024];
                ua[i].u[j] = lo | (hi << 16);
            }
        }
        #pragma unroll
        for (int j5 = 0; j5 < 4; ++j5) {
            #pragma unroll
            for (int j = 0; j < 4; ++j) {
                uint lo = vb0[j5 * 16 + (size_t)(2 * j) * 512];
                uint hi = vb0[j5 * 16 + (size_t)(2 * j + 1) * 512];
                ub[j5].u[j] = lo | (hi << 16);
            }
        }
        #pragma unroll
        for (int i = 0; i < 2; ++i) {
            #pragma unroll
            for (int j5 = 0; j5 < 4; ++j5)
                acc[i][j5] = __builtin_amdgcn_mfma_f32_16x16x32_bf16(ua[i].s, ub[j5].s, acc[i][j5], 0, 0, 0);
            acc[i][4] = __builtin_amdgcn_mfma_f32_16x16x32_bf16(ua[i].s, ones, acc[i][4], 0, 0, 0);
        }
        kf0 += (size_t)32 * 1024;
        vb0 += (size_t)32 * 512;
    }
    size_t base = ((size_t)(chunk * 64 + bh)) * 8320;
    #pragma unroll
    for (int i = 0; i < 2; ++i) {
        int d0 = w * 32 + i * 16 + (l >> 4) * 4;
        #pragma unroll
        for (int j = 0; j < 5; ++j) {
            int e = j * 16 + lr;
            if (j < 4 || e == 64)
                *(f32x4*)(PKV + base + (size_t)e * 128 + d0) = acc[i][j];
        }
    }
}

// ---------------- reduce partials -> pre-swizzled bf16 BT image [bh][80][128] ----------------
__global__ __launch_bounds__(256) void kvreduce2_kernel(const float* __restrict__ PKV,
                                                        ushort* __restrict__ kvTbf) {
    int gid = blockIdx.x * 256 + threadIdx.x;   // 64*80*128 = 655360
    const float inv_n = 1.0f / (float)NTOK;
    int bh = gid / 10240;
    int r  = gid - bh * 10240;
    int row = r >> 7, dcol = r & 127;
    int dlog = (((dcol >> 3) ^ (row & 7)) << 3) | (dcol & 7);
    float s = 0.f;
    if (row < 64) {
        int dsel = (row >= 32) ? (dlog ^ 64) : dlog;
        #pragma unroll
        for (int c = 0; c < 7; ++c) s += PKV[(size_t)c * 532480 + (size_t)bh * 8320 + row * 128 + dsel];
    } else if (row < 66) {
        int dsel = (row == 65) ? (dlog ^ 64) : dlog;
        #pragma unroll
        for (int c = 0; c < 7; ++c) s += PKV[(size_t)c * 532480 + (size_t)bh * 8320 + 64 * 128 + dsel];
    }
    kvTbf[gid] = (row < 66) ? f2bf(s * inv_n) : (ushort)0;
}

// ---------------- attention apply via MFMA (qfin fused), bf16 coalesced output ----------------
__global__ __launch_bounds__(256) void attn_mfma_kernel(const float* __restrict__ Q,
                                                        const float* __restrict__ QE,
                                                        const ushort* __restrict__ kvTbf,
                                                        const float* __restrict__ power,
                                                        const float* __restrict__ achan,
                                                        const float* __restrict__ bchan,
                                                        const float* __restrict__ invs,
                                                        const float* __restrict__ ewp,
                                                        ushort* __restrict__ ATTbf) {
    __shared__ ushort QF[64 * 128];
    __shared__ ushort BT[80 * 128];
    const int bh = blockIdx.x, tb = blockIdx.y;
    const int b = bh >> 3, head = bh & 7;
    const int t = threadIdx.x;
    const int w = t >> 6, l = t & 63;

    // stage pre-swizzled BT image (async)
    #pragma unroll
    for (int i = 0; i < 5; ++i) {
        int f = i * 256 + t;
        gload_lds16(kvTbf + (size_t)bh * 10240 + f * 8, BT + f * 8);
    }

    const int c = l, hc = head * 64 + c;
    const float p = power[hc];
    const float ac = achan[hc], bc = bchan[hc], iv = invs[hc], ew = ewp[0];
    #pragma unroll
    for (int i = 0; i < 16; ++i) {
        int tok = i * 4 + w;
        size_t off = ((size_t)(b * NTOK + tb * 64 + tok)) * CDIM + hc;
        float q = Q[off];
        float qe = QE[off];
        q = (q + ew * fmaxf(fmaf(ac, qe, bc), 0.f)) * iv;
        float ax = fabsf(q);
        float tp = ax > 0.f ? __powf(ax, p) : 0.f;
        float qp = q > 0.f ? tp : 0.f;
        float qn = q < 0.f ? tp : 0.f;
        int sw = tok & 7;
        QF[tok * 128 + (((c >> 3) ^ sw) * 8) + (c & 7)]       = f2bf(qp);
        QF[tok * 128 + ((((c >> 3) + 8) ^ sw) * 8) + (c & 7)] = f2bf(qn);
    }
    __syncthreads();

    f32x4 acc[5] = {};
    #pragma unroll
    for (int kk = 0; kk < 4; ++kk) {
        int sbase = kk * 4 + (l >> 4);
        int rowa = w * 16 + (l & 15);
        short8 af = *(const short8*)&QF[rowa * 128 + ((sbase ^ (rowa & 7)) * 8)];
        #pragma unroll
        for (int j = 0; j < 5; ++j) {
            int rowb = j * 16 + (l & 15);
            short8 bf = *(const short8*)&BT[rowb * 128 + ((sbase ^ (rowb & 7)) * 8)];
            acc[j] = __builtin_amdgcn_mfma_f32_16x16x32_bf16(af, bf, acc[j], 0, 0, 0);
        }
    }
    __syncthreads();   // QF reads complete before reuse as output staging

    ushort* Oout = QF; // 64 x 64
    #pragma unroll
    for (int rr = 0; rr < 4; ++rr) {
        float ssim = __shfl(acc[4][rr], (l & 48));
        float sopp = __shfl(acc[4][rr], (l & 48) + 1);
        float zs = 1.f / (ssim + 1e-6f);
        float zo = 1.f / (sopp + 1e-6f);
        int tokl = w * 16 + (l >> 4) * 4 + rr;
        #pragma unroll
        for (int j = 0; j < 4; ++j) {
            int e = j * 16 + (l & 15);
            Oout[tokl * 64 + e] = f2bf(acc[j][rr] * (j < 2 ? zs : zo));
        }
    }
    __syncthreads();

    #pragma unroll
    for (int i = 0; i < 2; ++i) {
        int idx = i * 256 + t;
        int tokl = idx >> 3, ch = (idx & 7) * 8;
        short8 vv = *(short8*)&Oout[tokl * 64 + ch];
        *(short8*)&ATTbf[((size_t)(b * NTOK + tb * 64 + tokl)) * CDIM + head * 64 + ch] = vv;
    }
}

// ---------------- v 5x5 depthwise conv (bf16 V) + gate (bf16 ATT) ----------------
__global__ __launch_bounds__(256) void voutg2_kernel(const ushort* __restrict__ Vbf,
                                                     const ushort* __restrict__ ATTbf,
                                                     const float* __restrict__ G,
                                                     const float* __restrict__ dwc_w,
                                                     const float* __restrict__ dwc_b,
                                                     ushort* __restrict__ PRE) {
    const int t = threadIdx.x;
    const int c0 = t * 2;
    const int xpos = blockIdx.x;
    const int byc = blockIdx.y;
    const int b = byc >> 2, yc = byc & 3;
    const int y0 = yc * 14;
    const int dch = c0 & 63;

    float wgt[25][2];
    #pragma unroll
    for (int tap = 0; tap < 25; ++tap) {
        wgt[tap][0] = dwc_w[dch * 25 + tap];
        wgt[tap][1] = dwc_w[(dch + 1) * 25 + tap];
    }
    const float bias0 = dwc_b[dch], bias1 = dwc_b[dch + 1];
    const size_t base = (size_t)b * NTOK * CDIM + c0;

    float2 win[5][5];
    auto ldrow = [&](int yy, float2* dst) {
        #pragma unroll
        for (int dx = 0; dx < 5; ++dx) {
            int xx = xpos + dx - 2;
            bool ok = (yy >= 0 && yy < HW && xx >= 0 && xx < HW);
            if (ok) {
                ushort2 uv = *(const ushort2*)(Vbf + base + ((size_t)(yy * HW + xx) << 9));
                dst[dx] = make_float2(bf2f(uv.x), bf2f(uv.y));
            } else {
                dst[dx] = make_float2(0.f, 0.f);
            }
        }
    };
    ldrow(y0 - 2, win[0]);
    ldrow(y0 - 1, win[1]);
    ldrow(y0,     win[2]);
    ldrow(y0 + 1, win[3]);

    #pragma unroll
    for (int i = 0; i < 14; ++i) {
        int y = y0 + i;
        ldrow(y + 2, win[(i + 4) % 5]);
        float a0 = bias0, a1 = bias1;
        #pragma unroll
        for (int dy = 0; dy < 5; ++dy) {
            float2* row = win[(i + dy) % 5];
            #pragma unroll
            for (int dx = 0; dx < 5; ++dx) {
                a0 = fmaf(row[dx].x, wgt[dy * 5 + dx][0], a0);
                a1 = fmaf(row[dx].y, wgt[dy * 5 + dx][1], a1);
            }
        }
        size_t oidx = base + ((size_t)(y * HW + xpos) << 9);
        ushort2 au = *(const ushort2*)(ATTbf + oidx);
        float2 g   = *(const float2*)(G + oidx);
        ushort2 o;
        o.x = f2bf((bf2f(au.x) + a0) * g.x);
        o.y = f2bf((bf2f(au.y) + a1) * g.y);
        *(ushort2*)(PRE + oidx) = o;
    }
}

extern "C" void kernel_launch(void* const* d_in, const int* in_sizes, int n_in,
                              void* d_out, int out_size, void* d_ws, size_t ws_size,
                              hipStream_t stream) {
    const float* x      = (const float*)d_in[0];
    const float* qg_w   = (const float*)d_in[1];
    const float* kv_w   = (const float*)d_in[2];
    const float* proj_w = (const float*)d_in[3];
    const float* proj_b = (const float*)d_in[4];
    const float* dwc_w  = (const float*)d_in[5];
    const float* dwc_b  = (const float*)d_in[6];
    const float* power_p= (const float*)d_in[7];
    const float* scale_p= (const float*)d_in[8];
    const float* enh_w  = (const float*)d_in[9];
    const float* bn_g   = (const float*)d_in[10];
    const float* bn_b   = (const float*)d_in[11];
    const float* ew_p   = (const float*)d_in[12];
    const float* pos    = (const float*)d_in[13];

    const size_t NELEM = (size_t)MTOT * CDIM;   // 12,845,056
    float* ws    = (float*)d_ws;
    float* Qb    = ws;                  // fp32 raw Q (live through attn)
    float* Gb    = ws + NELEM;          // fp32 G (live through voutg2)
    float* Kb    = ws + 2 * NELEM;      // KFbf ushort [0,NELEM); PKV floats [NELEM/2,..); later PREbf
    float* Vb    = ws + 3 * NELEM;      // Vbf ushort [0,NELEM); ATTbf ushort in upper half
    float* QEb   = ws + 4 * NELEM;      // Xbf, then QE fp32 (live through attn)
    float* SMALL = ws + 5 * NELEM;
    float* ssum  = SMALL;               // 512
    float* ssq   = SMALL + 512;         // 512
    ushort* kvTbf= (ushort*)(SMALL + 9216);      // 655,360 ushorts
    float* invs  = SMALL + 533504;      // 512
    float* powr  = SMALL + 534016;      // 512
    float* achan = SMALL + 534528;      // 512
    float* bchan = SMALL + 535040;      // 512
    ushort* Wqg  = (ushort*)(SMALL + 535552);    // 524288 bf16
    ushort* Wkv  = (ushort*)(SMALL + 797696);    // 524288 bf16
    ushort* Wproj= (ushort*)(SMALL + 1059840);   // 262144 bf16

    ushort* Xbf  = (ushort*)QEb;        // dead after qgkv gemm; conv3s overwrites with QE
    ushort* KFbf = (ushort*)Kb;         // dead after kvred4
    ushort* Vbf  = (ushort*)Vb;
    float* PKV   = Kb + NELEM / 2;      // 7*532480 = 3,727,360 floats (upper half of Kb)
    ushort* ATTbf= (ushort*)(Vb + NELEM / 2);    // NELEM ushorts (upper half of Vb)
    ushort* PREbf= (ushort*)Kb;         // proj input (KFbf+PKV dead by voutg2)

    hipMemsetAsync(SMALL, 0, (size_t)1024 * sizeof(float), stream);

    prep_kernel<<<1, 512, 0, stream>>>(scale_p, power_p, invs, powr);

    cvt_bf16_kernel<<<12544, 256, 0, stream>>>(x, Xbf, 3211264);
    cvt_bf16_kernel<<<512, 256, 0, stream>>>(qg_w, Wqg, 131072);
    cvt_bf16_kernel<<<512, 256, 0, stream>>>(kv_w, Wkv, 131072);
    cvt_bf16_kernel<<<256, 256, 0, stream>>>(proj_w, Wproj, 65536);

    mgemm_qgkv<<<3136, 256, 0, stream>>>(Xbf, Wqg, Wkv, Qb, Gb, KFbf, Vbf, pos, invs, powr);

    dim3 cgrid(56, 32);
    conv3s_kernel<<<cgrid, 256, 0, stream>>>(Qb, enh_w, QEb, ssum, ssq);
    bnprep_kernel<<<1, 512, 0, stream>>>(ssum, ssq, bn_g, bn_b, achan, bchan);

    kvred4_kernel<<<dim3(64, 7), 256, 0, stream>>>(KFbf, Vbf, PKV);
    kvreduce2_kernel<<<2560, 256, 0, stream>>>(PKV, kvTbf);

    attn_mfma_kernel<<<dim3(64, 49), 256, 0, stream>>>(Qb, QEb, kvTbf, powr,
                                                       achan, bchan, invs, ew_p, ATTbf);

    voutg2_kernel<<<cgrid, 256, 0, stream>>>(Vbf, ATTbf, Gb, dwc_w, dwc_b, PREbf);

    mgemm_proj<<<784, 256, 0, stream>>>(PREbf, Wproj, (float*)d_out, proj_b);
}